// Round 6
// baseline (450.101 us; speedup 1.0000x reference)
//
#include <hip/hip_runtime.h>
#include <hip/hip_bf16.h>

// Problem constants (N,C,H,W) = (32,256,56,56), GROUPS=8
#define NN 32
#define CC 256
#define HW4 784            // float4 per (n,c) plane
#define CHW4 200704        // float4 per sample
#define CHW 802816
#define NCHW 25690112
#define GROUPS 8
#define CPG 32             // C/GROUPS
#define NHW 100352         // N*H*W (per-channel count)
#define GHW 100352         // CPG*HW (per-group count)
#define EPSF 1e-5f

#define NBLK 1024          // 4 blocks/CU on 256 CUs -> all co-resident
#define PCHUNK 25          // f4 positions per chansum tile (32 tiles/sample)
#define FLAG_STRIDE 4      // uints between block flags (16B)
#define SPIN_MAX 40000000L // bounded spin so a logic bug can't hang the harness

// device-scope (cross-XCD coherent) scalar access — no cache-wide fences
__device__ inline void  stg_dev(float* p, float v) {
    __hip_atomic_store(p, v, __ATOMIC_RELAXED, __HIP_MEMORY_SCOPE_AGENT);
}
__device__ inline float ldg_dev(const float* p) {
    return __hip_atomic_load(p, __ATOMIC_RELAXED, __HIP_MEMORY_SCOPE_AGENT);
}

// ---- contention-free grid barrier: per-block flag stores + single releaser.
// flags[] and gen must be 0 at kernel start (memsetAsync'd each launch).
// target = barrier ordinal (1, 2, ...).
__device__ inline void flag_barrier(unsigned* flags, unsigned* gen, unsigned target)
{
    __syncthreads();   // all block lanes done; implicit vmcnt(0) drains stores
    const int tid = threadIdx.x;
    if (tid == 0) {
        __hip_atomic_store(&flags[(unsigned)blockIdx.x * FLAG_STRIDE], target,
                           __ATOMIC_RELEASE, __HIP_MEMORY_SCOPE_AGENT);
    }
    if (blockIdx.x == 0) {
        #pragma unroll
        for (int j = 0; j < NBLK / 256; ++j) {
            const unsigned idx = (unsigned)(tid + j * 256) * FLAG_STRIDE;
            for (long it = 0; it < SPIN_MAX; ++it) {
                if (__hip_atomic_load(&flags[idx], __ATOMIC_ACQUIRE,
                                      __HIP_MEMORY_SCOPE_AGENT) >= target) break;
                __builtin_amdgcn_s_sleep(2);
            }
        }
        __syncthreads();
        if (tid == 0)
            __hip_atomic_store(gen, target, __ATOMIC_RELEASE, __HIP_MEMORY_SCOPE_AGENT);
    }
    if (tid == 0) {
        for (long it = 0; it < SPIN_MAX; ++it) {
            if (__hip_atomic_load(gen, __ATOMIC_ACQUIRE,
                                  __HIP_MEMORY_SCOPE_AGENT) >= target) break;
            __builtin_amdgcn_s_sleep(4);
        }
    }
    __syncthreads();
}

__global__ __launch_bounds__(256, 4) void mega_kernel(
    const float4* __restrict__ x4,
    const float* __restrict__ weight, const float* __restrict__ bias,
    const float* __restrict__ gate_logits, const float* __restrict__ diag_proj,
    float4* __restrict__ y4,
    unsigned* flags, unsigned* gen,
    float* __restrict__ S1, float* __restrict__ S2,
    float* __restrict__ Aarr, float* __restrict__ Barr,
    float* __restrict__ pT2)
{
    const int tid  = threadIdx.x;
    const int wave = tid >> 6, lane = tid & 63;

    // =========== Phase A: per-(n,c) plane sums (one wave = one plane) =====
    #pragma unroll
    for (int rep = 0; rep < 2; ++rep) {
        const int plane = blockIdx.x * 4 + wave + rep * (NBLK * 4);
        const float4* p = x4 + (size_t)plane * HW4;
        float s1 = 0.f, s2 = 0.f;
        #pragma unroll 4
        for (int i = lane; i < HW4; i += 64) {
            float4 v = p[i];
            s1 += v.x + v.y + v.z + v.w;
            s2 += v.x*v.x + v.y*v.y + v.z*v.z + v.w*v.w;
        }
        #pragma unroll
        for (int off = 32; off; off >>= 1) {
            s1 += __shfl_down(s1, off, 64);
            s2 += __shfl_down(s2, off, 64);
        }
        if (lane == 0) { stg_dev(&S1[plane], s1); stg_dev(&S2[plane], s2); }
    }

    // =========== Phase B: cross-channel sums -> per-block T^2 partial =====
    {
        const int n = blockIdx.x >> 5, chunk = blockIdx.x & 31;
        const int start = chunk * PCHUNK;
        const int len = (HW4 - start) < PCHUNK ? (HW4 - start) : PCHUNK;
        const int cg = tid >> 5, p = tid & 31;
        float4 T = make_float4(0.f, 0.f, 0.f, 0.f);
        if (p < len) {
            const float4* q = x4 + (size_t)n * CHW4 + (size_t)(cg * 32) * HW4 + start + p;
            #pragma unroll 8
            for (int c = 0; c < 32; ++c) {
                float4 v = q[(size_t)c * HW4];
                T.x += v.x; T.y += v.y; T.z += v.z; T.w += v.w;
            }
        }
        __shared__ float4 shT[32];
        #pragma unroll
        for (int k = 0; k < 8; ++k) {
            if (cg == k) {
                if (k == 0) shT[p] = T;
                else { shT[p].x += T.x; shT[p].y += T.y; shT[p].z += T.z; shT[p].w += T.w; }
            }
            __syncthreads();
        }
        float t2 = 0.f;
        if (tid < 32) {
            float4 t = shT[tid];
            t2 = t.x*t.x + t.y*t.y + t.z*t.z + t.w*t.w;
        }
        #pragma unroll
        for (int off = 32; off; off >>= 1) t2 += __shfl_down(t2, off, 64);
        if (tid == 0) stg_dev(&pT2[blockIdx.x], t2);
    }

    flag_barrier(flags, gen, 1u);

    // =========== Phase C: finalize on block 0 only ========================
    if (blockIdx.x == 0) {
        __shared__ float sh_mu_b[CC], sh_rs_b[CC];
        __shared__ float sh_mu_g[NN * GROUPS], sh_rs_g[NN * GROUPS];
        __shared__ float sh_mu_l[NN], sh_rs_l[NN];
        __shared__ float sh_red1[4], sh_red2[4], sh_red3[4], sh_red4[4];
        __shared__ float sh_gate[3];

        const float inv_NHW  = 1.f / (float)NHW;
        const float inv_CHW  = 1.f / (float)CHW;
        const float inv_GHW  = 1.f / (float)GHW;
        const float inv_NCHW = 1.f / (float)NCHW;

        // BN: thread = channel
        const int c = tid;
        float s1 = 0.f, s2 = 0.f;
        for (int n = 0; n < NN; ++n) {
            s1 += ldg_dev(&S1[n * CC + c]);
            s2 += ldg_dev(&S2[n * CC + c]);
        }
        const float mu_b  = s1 * inv_NHW;
        const float var_b = s2 * inv_NHW - mu_b * mu_b;
        sh_mu_b[c] = mu_b;
        sh_rs_b[c] = rsqrtf(var_b + EPSF);

        // GN: thread = n*8+g
        const int ng_n = tid >> 3, ng_g = tid & 7;
        float s1g = 0.f, s2g = 0.f;
        for (int cc2 = 0; cc2 < CPG; ++cc2) {
            const int idx = ng_n * CC + ng_g * CPG + cc2;
            s1g += ldg_dev(&S1[idx]); s2g += ldg_dev(&S2[idx]);
        }
        const float mu_g  = s1g * inv_GHW;
        const float var_g = s2g * inv_GHW - mu_g * mu_g;
        sh_mu_g[tid] = mu_g;
        sh_rs_g[tid] = rsqrtf(var_g + EPSF);

        // LN: reduce GN sums over 8 groups per sample
        float s1l = s1g, s2l = s2g;
        #pragma unroll
        for (int off = 1; off < 8; off <<= 1) {
            s1l += __shfl_xor(s1l, off, 64);
            s2l += __shfl_xor(s2l, off, 64);
        }
        float var_l_contrib = 0.f;
        if (ng_g == 0) {
            const float mu_l  = s1l * inv_CHW;
            const float var_l = s2l * inv_CHW - mu_l * mu_l;
            sh_mu_l[ng_n] = mu_l;
            sh_rs_l[ng_n] = rsqrtf(var_l + EPSF);
            var_l_contrib = var_l;
        }

        // T^2 partials
        float t2p = 0.f;
        for (int i = tid; i < NBLK; i += 256) t2p += ldg_dev(&pT2[i]);

        float r1 = var_b, r2 = s2, r3 = var_l_contrib, r4 = t2p;
        #pragma unroll
        for (int off = 32; off; off >>= 1) {
            r1 += __shfl_down(r1, off, 64);
            r2 += __shfl_down(r2, off, 64);
            r3 += __shfl_down(r3, off, 64);
            r4 += __shfl_down(r4, off, 64);
        }
        if (lane == 0) { sh_red1[wave] = r1; sh_red2[wave] = r2; sh_red3[wave] = r3; sh_red4[wave] = r4; }
        __syncthreads();
        if (tid == 0) {
            const float sum_var_b = sh_red1[0] + sh_red1[1] + sh_red1[2] + sh_red1[3];
            const float total_x2  = sh_red2[0] + sh_red2[1] + sh_red2[2] + sh_red2[3];
            const float sum_var_l = sh_red3[0] + sh_red3[1] + sh_red3[2] + sh_red3[3];
            const float sum_T2    = sh_red4[0] + sh_red4[1] + sh_red4[2] + sh_red4[3];

            const float batch_var   = sum_var_b * (1.f / (float)CC);
            const float sample_var  = sum_var_l * (1.f / (float)NN);
            const float channel_var = total_x2 * inv_NCHW
                                    - sum_T2 * inv_NHW * (1.f / ((float)CC * (float)CC));

            float desc[3];
            desc[0] = tanhf(logf(fmaxf(batch_var,   EPSF)));
            desc[1] = tanhf(logf(fmaxf(sample_var,  EPSF)));
            desc[2] = tanhf(logf(fmaxf(channel_var, EPSF)));

            float lg[3];
            #pragma unroll
            for (int i = 0; i < 3; ++i) {
                lg[i] = gate_logits[i] + diag_proj[i*3+0]*desc[0]
                                       + diag_proj[i*3+1]*desc[1]
                                       + diag_proj[i*3+2]*desc[2];
            }
            const float m = fmaxf(lg[0], fmaxf(lg[1], lg[2]));
            const float e0 = expf(lg[0]-m), e1 = expf(lg[1]-m), e2 = expf(lg[2]-m);
            const float inv = 1.f / (e0 + e1 + e2);
            sh_gate[0] = e0 * inv; sh_gate[1] = e1 * inv; sh_gate[2] = e2 * inv;
        }
        __syncthreads();

        const float g0 = sh_gate[0], g1 = sh_gate[1], g2 = sh_gate[2];
        for (int i = tid; i < NN * CC; i += 256) {
            const int n = i >> 8, ch = i & 255, g = ch >> 5;
            const float w = weight[ch], bi = bias[ch];
            const float rb = sh_rs_b[ch], rl = sh_rs_l[n], rg = sh_rs_g[n*8+g];
            const float mb = sh_mu_b[ch], ml = sh_mu_l[n], mg = sh_mu_g[n*8+g];
            const float scale = g0*rb + g1*rl + g2*rg;
            const float offs  = g0*mb*rb + g1*ml*rl + g2*mg*rg;
            stg_dev(&Aarr[i], w * scale);
            stg_dev(&Barr[i], bi - w * offs);
        }
    }

    flag_barrier(flags, gen, 2u);

    // =========== Phase D: apply y = x*A[nc] + B[nc] =======================
    float av[8], bv[8];
    #pragma unroll
    for (int j = 0; j < 8; ++j) {
        const int plane = blockIdx.x + j * NBLK;
        av[j] = ldg_dev(&Aarr[plane]);
        bv[j] = ldg_dev(&Barr[plane]);
    }
    #pragma unroll
    for (int j = 0; j < 8; ++j) {
        const int plane = blockIdx.x + j * NBLK;
        const float a = av[j], b = bv[j];
        const float4* xp = x4 + (size_t)plane * HW4;
        float4* yp = y4 + (size_t)plane * HW4;
        for (int i = tid; i < HW4; i += 256) {
            float4 v = xp[i];
            v.x = fmaf(v.x, a, b);
            v.y = fmaf(v.y, a, b);
            v.z = fmaf(v.z, a, b);
            v.w = fmaf(v.w, a, b);
            yp[i] = v;
        }
    }
}

extern "C" void kernel_launch(void* const* d_in, const int* in_sizes, int n_in,
                              void* d_out, int out_size, void* d_ws, size_t ws_size,
                              hipStream_t stream) {
    const float* x           = (const float*)d_in[0];
    const float* weight      = (const float*)d_in[1];
    const float* bias        = (const float*)d_in[2];
    const float* gate_logits = (const float*)d_in[3];
    const float* diag_proj   = (const float*)d_in[4];
    float* out = (float*)d_out;

    // ws layout (floats/uints):
    //   [0      .. 4095 ] flags  (1024 * FLAG_STRIDE uints, 16 KB)
    //   [4096]            gen
    //   [4112  .. ]       S1(8192) S2(8192) A(8192) B(8192) pT2(1024)
    unsigned* flags = (unsigned*)d_ws;
    unsigned* gen   = flags + 4096;
    float* wsf  = (float*)d_ws;
    float* S1   = wsf + 4112;
    float* S2   = S1 + 8192;
    float* Aarr = S2 + 8192;
    float* Barr = Aarr + 8192;
    float* pT2  = Barr + 8192;

    // flags+gen must be 0 at kernel start; captured as a graph node.
    hipMemsetAsync(flags, 0, (4096 + 16) * sizeof(unsigned), stream);

    mega_kernel<<<NBLK, 256, 0, stream>>>(
        (const float4*)x, weight, bias, gate_logits, diag_proj,
        (float4*)out, flags, gen, S1, S2, Aarr, Barr, pT2);
}

// Round 7
// 77.773 us; speedup vs baseline: 5.7874x; 5.7874x over previous
//
#include <hip/hip_runtime.h>
#include <hip/hip_bf16.h>

// Problem constants (N,C,H,W) = (32,256,56,56), GROUPS=8
#define NN 32
#define CC 256
#define HW 3136            // H*W
#define HW4 784            // float4 per (n,c) plane
#define CHW 802816
#define CHW4 200704        // float4 per sample
#define NCHW 25690112
#define GROUPS 8
#define CPG 32             // C/GROUPS
#define NHW 100352         // N*H*W (per-channel count)
#define GHW 100352         // CPG*HW (per-group count)
#define EPSF 1e-5f

#define NPOS4 25088        // total float4 positions = NN*HW4 (= 98*256 exactly)
#define POSBLK 98          // position blocks (256 f4-positions each)
#define CGS 8              // channel groups for chansum
#define CPB 32             // channels per chansum block (CC/CGS)
#define NPT2 POSBLK        // 98 T^2 partials

// ---- kernel 1: per-(n,c) plane sums; one wave = one full plane -----------
// grid = 2048 blocks (4 waves = 4 planes per block). HBM-bound pass.
__global__ __launch_bounds__(256) void plane_stats_kernel(
    const float4* __restrict__ x4, float* __restrict__ S1, float* __restrict__ S2)
{
    const int wave = threadIdx.x >> 6, lane = threadIdx.x & 63;
    const int nc = blockIdx.x * 4 + wave;
    const float4* p = x4 + (size_t)nc * HW4;
    float s1 = 0.f, s2 = 0.f;
    #pragma unroll
    for (int j = 0; j < 12; ++j) {             // 12*64 = 768 always valid
        float4 v = p[lane + j * 64];
        s1 += v.x + v.y + v.z + v.w;
        s2 += v.x*v.x + v.y*v.y + v.z*v.z + v.w*v.w;
    }
    if (lane < 16) {                           // tail 768..783
        float4 v = p[768 + lane];
        s1 += v.x + v.y + v.z + v.w;
        s2 += v.x*v.x + v.y*v.y + v.z*v.z + v.w*v.w;
    }
    #pragma unroll
    for (int off = 32; off; off >>= 1) {
        s1 += __shfl_down(s1, off, 64);
        s2 += __shfl_down(s2, off, 64);
    }
    if (lane == 0) { S1[nc] = s1; S2[nc] = s2; }
}

// ---- kernel 2: position-parallel partial channel sums --------------------
// grid = CGS*POSBLK = 784 blocks; thread = one f4 position, 32 independent
// float4 loads over its channel group; no reductions, no LDS.
__global__ __launch_bounds__(256) void chansum_kernel(
    const float4* __restrict__ x4, float4* __restrict__ pT4)
{
    const int cg = blockIdx.x / POSBLK;
    const int pb = blockIdx.x % POSBLK;
    const int pos = pb * 256 + threadIdx.x;    // 0..25087, exact fit
    const int n = pos / HW4;
    const int p4 = pos - n * HW4;
    const float4* q = x4 + (size_t)n * CHW4 + (size_t)(cg * CPB) * HW4 + p4;
    float4 T = make_float4(0.f, 0.f, 0.f, 0.f);
    #pragma unroll 8
    for (int c = 0; c < CPB; ++c) {
        float4 v = q[(size_t)c * HW4];
        T.x += v.x; T.y += v.y; T.z += v.z; T.w += v.w;
    }
    pT4[(size_t)cg * NPOS4 + pos] = T;
}

// ---- kernel 3: fold 8 channel groups, square, block-reduce -> pT2[98] ----
__global__ __launch_bounds__(256) void combine_kernel(
    const float4* __restrict__ pT4, float* __restrict__ pT2)
{
    const int tid = threadIdx.x;
    const int pos = blockIdx.x * 256 + tid;
    float4 T = make_float4(0.f, 0.f, 0.f, 0.f);
    #pragma unroll
    for (int cg = 0; cg < CGS; ++cg) {
        float4 v = pT4[(size_t)cg * NPOS4 + pos];
        T.x += v.x; T.y += v.y; T.z += v.z; T.w += v.w;
    }
    float t2 = T.x*T.x + T.y*T.y + T.z*T.z + T.w*T.w;
    #pragma unroll
    for (int off = 32; off; off >>= 1) t2 += __shfl_down(t2, off, 64);
    __shared__ float sh[4];
    const int wave = tid >> 6, lane = tid & 63;
    if (lane == 0) sh[wave] = t2;
    __syncthreads();
    if (tid == 0) pT2[blockIdx.x] = sh[0] + sh[1] + sh[2] + sh[3];
}

// ---- kernel 4: all stats -> gates -> per-(n,c) affine coeffs A,B ---------
__global__ __launch_bounds__(256) void finalize_kernel(
    const float* __restrict__ S1, const float* __restrict__ S2,
    const float* __restrict__ partialT2,
    const float* __restrict__ weight, const float* __restrict__ bias,
    const float* __restrict__ gate_logits, const float* __restrict__ diag_proj,
    float* __restrict__ A, float* __restrict__ B)
{
    const int tid = threadIdx.x;
    __shared__ float sh_mu_b[CC], sh_rs_b[CC];
    __shared__ float sh_mu_g[NN * GROUPS], sh_rs_g[NN * GROUPS];
    __shared__ float sh_mu_l[NN], sh_rs_l[NN];
    __shared__ float sh_red1[4], sh_red2[4], sh_red3[4], sh_red4[4];
    __shared__ float sh_gate[3];

    const float inv_NHW  = 1.f / (float)NHW;
    const float inv_CHW  = 1.f / (float)CHW;
    const float inv_GHW  = 1.f / (float)GHW;
    const float inv_NCHW = 1.f / (float)NCHW;

    // BN: thread = channel
    const int c = tid;
    float s1 = 0.f, s2 = 0.f;
    for (int n = 0; n < NN; ++n) { s1 += S1[n * CC + c]; s2 += S2[n * CC + c]; }
    const float mu_b  = s1 * inv_NHW;
    const float var_b = s2 * inv_NHW - mu_b * mu_b;
    sh_mu_b[c] = mu_b;
    sh_rs_b[c] = rsqrtf(var_b + EPSF);

    // GN: thread = n*8+g
    const int ng_n = tid >> 3, ng_g = tid & 7;
    float s1g = 0.f, s2g = 0.f;
    for (int cc2 = 0; cc2 < CPG; ++cc2) {
        const int idx = ng_n * CC + ng_g * CPG + cc2;
        s1g += S1[idx]; s2g += S2[idx];
    }
    const float mu_g  = s1g * inv_GHW;
    const float var_g = s2g * inv_GHW - mu_g * mu_g;
    sh_mu_g[tid] = mu_g;
    sh_rs_g[tid] = rsqrtf(var_g + EPSF);

    // LN: reduce GN sums over the 8 groups of each sample
    float s1l = s1g, s2l = s2g;
    #pragma unroll
    for (int off = 1; off < 8; off <<= 1) {
        s1l += __shfl_xor(s1l, off, 64);
        s2l += __shfl_xor(s2l, off, 64);
    }
    float var_l_contrib = 0.f;
    if (ng_g == 0) {
        const float mu_l  = s1l * inv_CHW;
        const float var_l = s2l * inv_CHW - mu_l * mu_l;
        sh_mu_l[ng_n] = mu_l;
        sh_rs_l[ng_n] = rsqrtf(var_l + EPSF);
        var_l_contrib = var_l;
    }

    // T^2 partials
    float t2p = 0.f;
    for (int i = tid; i < NPT2; i += 256) t2p += partialT2[i];

    float r1 = var_b, r2 = s2, r3 = var_l_contrib, r4 = t2p;
    #pragma unroll
    for (int off = 32; off; off >>= 1) {
        r1 += __shfl_down(r1, off, 64);
        r2 += __shfl_down(r2, off, 64);
        r3 += __shfl_down(r3, off, 64);
        r4 += __shfl_down(r4, off, 64);
    }
    const int wave = tid >> 6, lane = tid & 63;
    if (lane == 0) { sh_red1[wave] = r1; sh_red2[wave] = r2; sh_red3[wave] = r3; sh_red4[wave] = r4; }
    __syncthreads();
    if (tid == 0) {
        const float sum_var_b = sh_red1[0] + sh_red1[1] + sh_red1[2] + sh_red1[3];
        const float total_x2  = sh_red2[0] + sh_red2[1] + sh_red2[2] + sh_red2[3];
        const float sum_var_l = sh_red3[0] + sh_red3[1] + sh_red3[2] + sh_red3[3];
        const float sum_T2    = sh_red4[0] + sh_red4[1] + sh_red4[2] + sh_red4[3];

        const float batch_var   = sum_var_b * (1.f / (float)CC);
        const float sample_var  = sum_var_l * (1.f / (float)NN);
        const float channel_var = total_x2 * inv_NCHW
                                - sum_T2 * inv_NHW * (1.f / ((float)CC * (float)CC));

        float desc[3];
        desc[0] = tanhf(logf(fmaxf(batch_var,   EPSF)));
        desc[1] = tanhf(logf(fmaxf(sample_var,  EPSF)));
        desc[2] = tanhf(logf(fmaxf(channel_var, EPSF)));

        float lg[3];
        #pragma unroll
        for (int i = 0; i < 3; ++i) {
            lg[i] = gate_logits[i] + diag_proj[i*3+0]*desc[0]
                                   + diag_proj[i*3+1]*desc[1]
                                   + diag_proj[i*3+2]*desc[2];
        }
        const float m = fmaxf(lg[0], fmaxf(lg[1], lg[2]));
        const float e0 = expf(lg[0]-m), e1 = expf(lg[1]-m), e2 = expf(lg[2]-m);
        const float inv = 1.f / (e0 + e1 + e2);
        sh_gate[0] = e0 * inv; sh_gate[1] = e1 * inv; sh_gate[2] = e2 * inv;
    }
    __syncthreads();

    const float g0 = sh_gate[0], g1 = sh_gate[1], g2 = sh_gate[2];
    for (int i = tid; i < NN * CC; i += 256) {
        const int n = i >> 8, ch = i & 255, g = ch >> 5;
        const float w = weight[ch], bi = bias[ch];
        const float rb = sh_rs_b[ch], rl = sh_rs_l[n], rg = sh_rs_g[n*8+g];
        const float mb = sh_mu_b[ch], ml = sh_mu_l[n], mg = sh_mu_g[n*8+g];
        const float scale = g0*rb + g1*rl + g2*rg;
        const float offs  = g0*mb*rb + g1*ml*rl + g2*mg*rg;
        A[i] = w * scale;
        B[i] = bi - w * offs;
    }
}

// ---- kernel 5: y = x*A[nc] + B[nc], one block per (n,c) plane ------------
__global__ __launch_bounds__(256) void apply_kernel(
    const float4* __restrict__ x4, const float* __restrict__ A,
    const float* __restrict__ B, float4* __restrict__ y4)
{
    const int nc = blockIdx.x;
    const float a = A[nc], b = B[nc];
    const float4* xp = x4 + (size_t)nc * HW4;
    float4* yp = y4 + (size_t)nc * HW4;
    for (int i = threadIdx.x; i < HW4; i += 256) {
        float4 v = xp[i];
        v.x = fmaf(v.x, a, b);
        v.y = fmaf(v.y, a, b);
        v.z = fmaf(v.z, a, b);
        v.w = fmaf(v.w, a, b);
        yp[i] = v;
    }
}

extern "C" void kernel_launch(void* const* d_in, const int* in_sizes, int n_in,
                              void* d_out, int out_size, void* d_ws, size_t ws_size,
                              hipStream_t stream) {
    const float* x           = (const float*)d_in[0];
    const float* weight      = (const float*)d_in[1];
    const float* bias        = (const float*)d_in[2];
    const float* gate_logits = (const float*)d_in[3];
    const float* diag_proj   = (const float*)d_in[4];
    float* out = (float*)d_out;

    float* ws   = (float*)d_ws;
    float* S1   = ws;                 // 8192
    float* S2   = ws + 8192;          // 8192
    float* A    = ws + 16384;         // 8192
    float* B    = ws + 24576;         // 8192
    float* pT2  = ws + 32768;         // 98 (pad to 128)
    float* pT4f = ws + 32896;         // CGS*NPOS4*4 = 802816 floats (3.2 MB);
                                      // 32896*4 % 16 == 0 -> float4-aligned

    plane_stats_kernel<<<2048, 256, 0, stream>>>((const float4*)x, S1, S2);
    chansum_kernel<<<CGS * POSBLK, 256, 0, stream>>>((const float4*)x, (float4*)pT4f);
    combine_kernel<<<POSBLK, 256, 0, stream>>>((const float4*)pT4f, pT2);
    finalize_kernel<<<1, 256, 0, stream>>>(S1, S2, pT2, weight, bias,
                                           gate_logits, diag_proj, A, B);
    apply_kernel<<<NN * CC, 256, 0, stream>>>((const float4*)x, A, B, (float4*)out);
}